// Round 8
// baseline (119.549 us; speedup 1.0000x reference)
//
#include <hip/hip_runtime.h>
#include <hip/hip_bf16.h>

// GMM NLL: N=524288 rows, P=16, G=8.
// R8: harness floor ~75-80us (256MiB ws re-poison fill + restores) dominates;
//   squeeze the ~15-20us controllable part:
//   - gmm_prep: wave-synchronous (ZERO __syncthreads). Each group's 16
//     threads are within one wave; volatile LDS + in-wave DS ordering
//     replaces 32 barriers. Packing remapped so each wave packs only its
//     own groups; per-group lane computes its own lcoef.
//   - gmm_main: X loaded directly in MFMA-B layout (lane = (row n, K-half));
//     removes the LDS pack/store/barrier/read round-trip and the jac
//     ds_bpermute (jac = per-lane partial + the xor-32 shuffle we already do).
//     Quad pipeline (32x32x16 bf16 MFMA, AU/b1 init trick) identical to R7
//     (absmax 0).
//   - reduce: unchanged (plain per-block partial stores, 1-block sum).

#define P 16
#define G 8

typedef short bf16x8 __attribute__((ext_vector_type(8)));
typedef float f32x16 __attribute__((ext_vector_type(16)));

__device__ __forceinline__ unsigned short f2bf(float f) {
    unsigned u = __builtin_bit_cast(unsigned, f);
    return (unsigned short)((u + 0x7FFFu + ((u >> 16) & 1u)) >> 16);  // RNE
}

// ws float-offset layout:
//   [0,1024)    A-frags: ushort[4 pairs][64 lanes][8]  (4 KB)
//   [1024,1280) u-frags: uint[4 pairs][64 lanes] (low16 = bf16(-u) for lane<32 else 0)
//   [1280,1288) lcoef[G]
//   [1288,1336) lam[P], lam-1[P], 1/lam[P]
//   [4096,6144) per-block partials (2048 floats)
#define UFRAG_F 1024
#define WS_LC   1280
#define WS_LAM  1288
#define WS_LM1  1304
#define WS_RL   1320
#define WS_PART 4096

__global__ __launch_bounds__(128) void gmm_prep(const float* __restrict__ lambdas,
                                                const float* __restrict__ mus,
                                                const float* __restrict__ sigmas,
                                                const float* __restrict__ w,
                                                float* __restrict__ ws) {
    // All cross-thread deps are within one wave (group g = tid>>4, 4 groups
    // per wave). volatile + in-wave DS ordering => no __syncthreads needed.
    volatile __shared__ float Lsh[G][P][P];
    volatile __shared__ float Vsh[G][P][P];
    volatile __shared__ float ush[G][P];
    const int tid  = threadIdx.x;
    const int lane = tid & 63;
    const int wid  = tid >> 6;
    const int g = tid >> 4;
    const int r = tid & 15;

    // left-looking Cholesky; thread r owns row r of group g.
#pragma unroll
    for (int j = 0; j < P; ++j) {
        float s = sigmas[g * P * P + r * P + j];
#pragma unroll
        for (int k = 0; k < j; ++k) s -= Lsh[g][r][k] * Lsh[g][j][k];
        if (r == j) Lsh[g][j][j] = sqrtf(s);          // write precedes reads below (in-wave order)
        if (r > j)  Lsh[g][r][j] = s / Lsh[g][j][j];
    }

    // V = L^{-1}: thread r builds column r (only reads own column + L rows).
#pragma unroll
    for (int i = 0; i < P; ++i) {
        float s = 0.f;
#pragma unroll
        for (int k = 0; k < i; ++k) s += Lsh[g][i][k] * Vsh[g][k][r];
        const float rii = 1.0f / Lsh[g][i][i];
        Vsh[g][i][r] = (i == r) ? rii : ((i < r) ? 0.f : -s * rii);
    }

    // u_g[r] = (V_g mu_g)[r]  (reads row r of V: all columns written above,
    // wave lockstep guarantees completion in program order)
    {
        float u = 0.f;
#pragma unroll
        for (int j = 0; j < P; ++j) u = fmaf(Vsh[g][r][j], mus[g * P + j], u);
        ush[g][r] = u;
    }

    // per-group lcoef by the group's r==0 thread (softmax recomputed per
    // group from global w -- trivial, keeps everything group-local)
    if (r == 0) {
        float ld = 0.f;
#pragma unroll
        for (int j = 0; j < P; ++j) ld += __logf(Lsh[g][j][j]);
        float wm = w[0];
#pragma unroll
        for (int k = 1; k < G; ++k) wm = fmaxf(wm, w[k]);
        float ssum = 0.f;
#pragma unroll
        for (int k = 0; k < G; ++k) ssum += __expf(w[k] - wm);
        const float lse = wm + __logf(ssum);
        const float lead = -14.7030165f; // -0.5 * 16 * ln(2*pi)
        ws[WS_LC + g] = (w[g] - lse) + lead - ld;   // -0.5*logdet = -ld
    }

    // Fragment tables for mfma_f32_32x32x16_bf16. Wave w packs pairs
    // {2w, 2w+1} = groups {4w..4w+3} -- its OWN groups, no cross-wave deps.
    unsigned short* ws16 = (unsigned short*)ws;
    unsigned* wsu32 = (unsigned*)(ws + UFRAG_F);
#pragma unroll
    for (int pp = 0; pp < 2; ++pp) {
        const int p = wid * 2 + pp;
        const int m = lane & 31, half = lane >> 5;
        const int grp = 2 * p + (m >> 4), i = m & 15;
        unsigned short* dst = ws16 + (p * 64 + lane) * 8;
#pragma unroll
        for (int j = 0; j < 8; ++j) dst[j] = f2bf(Vsh[grp][i][half * 8 + j]);
        wsu32[p * 64 + lane] = (half == 0) ? (unsigned)f2bf(-ush[grp][i]) : 0u;
    }

    if (tid < P) {
        float lam = lambdas[tid];
        ws[WS_LAM + tid] = lam;
        ws[WS_LM1 + tid] = lam - 1.0f;
        ws[WS_RL  + tid] = 1.0f / lam;
    }
}

__global__ __launch_bounds__(256, 4) void gmm_main(const float* __restrict__ X,
                                                   const float* __restrict__ ws,
                                                   float* __restrict__ partials,
                                                   int nrows) {
    __shared__ float red[4];

    const int tid  = threadIdx.x;
    const int lane = tid & 63;
    const int wid  = tid >> 6;
    const int n    = lane & 31;      // data-row within tile
    const bool h   = (lane >= 32);   // K-half / quadrant
    const unsigned short* ws16 = (const unsigned short*)ws;
    const unsigned* wsu32 = (const unsigned*)(ws + UFRAG_F);

    // resident fragments
    const bf16x8 av0 = *(const bf16x8*)(ws16 + (0 * 64 + lane) * 8);
    const bf16x8 av1 = *(const bf16x8*)(ws16 + (1 * 64 + lane) * 8);
    const bf16x8 av2 = *(const bf16x8*)(ws16 + (2 * 64 + lane) * 8);
    const bf16x8 av3 = *(const bf16x8*)(ws16 + (3 * 64 + lane) * 8);
    bf16x8 au0 = {0,0,0,0,0,0,0,0}; au0[0] = (short)wsu32[0 * 64 + lane];
    bf16x8 au1 = {0,0,0,0,0,0,0,0}; au1[0] = (short)wsu32[1 * 64 + lane];
    bf16x8 au2 = {0,0,0,0,0,0,0,0}; au2[0] = (short)wsu32[2 * 64 + lane];
    bf16x8 au3 = {0,0,0,0,0,0,0,0}; au3[0] = (short)wsu32[3 * 64 + lane];
    bf16x8 b1 = {0,0,0,0,0,0,0,0};
    if (!h) b1[0] = (short)0x3F80;   // B1[k][n] = (k==0): homogeneous ones

    // per-half transform constants, selected once (wave-uniform s_loads + cndmask)
#define SEL(base, e) (h ? ws[(base) + 8 + (e)] : ws[(base) + (e)])
    const float la0 = SEL(WS_LAM,0), la1 = SEL(WS_LAM,1), la2 = SEL(WS_LAM,2), la3 = SEL(WS_LAM,3),
                la4 = SEL(WS_LAM,4), la5 = SEL(WS_LAM,5), la6 = SEL(WS_LAM,6), la7 = SEL(WS_LAM,7);
    const float lm0 = SEL(WS_LM1,0), lm1_ = SEL(WS_LM1,1), lm2 = SEL(WS_LM1,2), lm3 = SEL(WS_LM1,3),
                lm4 = SEL(WS_LM1,4), lm5 = SEL(WS_LM1,5), lm6 = SEL(WS_LM1,6), lm7 = SEL(WS_LM1,7);
    const float rl0 = SEL(WS_RL,0), rl1 = SEL(WS_RL,1), rl2 = SEL(WS_RL,2), rl3 = SEL(WS_RL,3),
                rl4 = SEL(WS_RL,4), rl5 = SEL(WS_RL,5), rl6 = SEL(WS_RL,6), rl7 = SEL(WS_RL,7);
#undef SEL

    float nll = 0.f;

#define PAIR(AV, AU, SA, SB) { \
    f32x16 acc = {}; \
    acc = __builtin_amdgcn_mfma_f32_32x32x16_bf16(AU, b1, acc, 0, 0, 0); \
    acc = __builtin_amdgcn_mfma_f32_32x32x16_bf16(AV, bx, acc, 0, 0, 0); \
    float sa = acc[0] * acc[0];    float sb = acc[8] * acc[8]; \
    sa = fmaf(acc[1], acc[1], sa); sb = fmaf(acc[9],  acc[9],  sb); \
    sa = fmaf(acc[2], acc[2], sa); sb = fmaf(acc[10], acc[10], sb); \
    sa = fmaf(acc[3], acc[3], sa); sb = fmaf(acc[11], acc[11], sb); \
    sa = fmaf(acc[4], acc[4], sa); sb = fmaf(acc[12], acc[12], sb); \
    sa = fmaf(acc[5], acc[5], sa); sb = fmaf(acc[13], acc[13], sb); \
    sa = fmaf(acc[6], acc[6], sa); sb = fmaf(acc[14], acc[14], sb); \
    sa = fmaf(acc[7], acc[7], sa); sb = fmaf(acc[15], acc[15], sb); \
    SA = sa; SB = sb; }

#define TILE(t_) { \
    const int row = blockIdx.x * 256 + wid * 64 + t_ * 32 + n; \
    const int rc = row < nrows ? row : nrows - 1; \
    const float* xp = X + (size_t)rc * P + (h ? 8 : 0); \
    const float4 xa = *(const float4*)xp; \
    const float4 xb = *(const float4*)(xp + 4); \
    float jp = 0.f; \
    const float l0 = __logf(xa.x), l1 = __logf(xa.y), l2 = __logf(xa.z), l3 = __logf(xa.w); \
    const float l4 = __logf(xb.x), l5 = __logf(xb.y), l6 = __logf(xb.z), l7 = __logf(xb.w); \
    const float x0 = (__expf(la0 * l0) - 1.f) * rl0;  jp = fmaf(l0, lm0, jp); \
    const float x1 = (__expf(la1 * l1) - 1.f) * rl1;  jp = fmaf(l1, lm1_, jp); \
    const float x2 = (__expf(la2 * l2) - 1.f) * rl2;  jp = fmaf(l2, lm2, jp); \
    const float x3 = (__expf(la3 * l3) - 1.f) * rl3;  jp = fmaf(l3, lm3, jp); \
    const float x4 = (__expf(la4 * l4) - 1.f) * rl4;  jp = fmaf(l4, lm4, jp); \
    const float x5 = (__expf(la5 * l5) - 1.f) * rl5;  jp = fmaf(l5, lm5, jp); \
    const float x6 = (__expf(la6 * l6) - 1.f) * rl6;  jp = fmaf(l6, lm6, jp); \
    const float x7 = (__expf(la7 * l7) - 1.f) * rl7;  jp = fmaf(l7, lm7, jp); \
    bf16x8 bx; \
    bx[0] = (short)f2bf(x0); bx[1] = (short)f2bf(x1); \
    bx[2] = (short)f2bf(x2); bx[3] = (short)f2bf(x3); \
    bx[4] = (short)f2bf(x4); bx[5] = (short)f2bf(x5); \
    bx[6] = (short)f2bf(x6); bx[7] = (short)f2bf(x7); \
    const float jn = jp + __shfl_xor(jp, 32, 64); \
    float pa0, pa1, pa2, pa3, pb0, pb1, pb2, pb3; \
    PAIR(av0, au0, pa0, pb0) PAIR(av1, au1, pa1, pb1) \
    PAIR(av2, au2, pa2, pb2) PAIR(av3, au3, pa3, pb3) \
    const float k0 = h ? pa2 : pa0, s0 = h ? pa0 : pa2; \
    const float k1 = h ? pb2 : pb0, s1 = h ? pb0 : pb2; \
    const float k2 = h ? pa3 : pa1, s2 = h ? pa1 : pa3; \
    const float k3 = h ? pb3 : pb1, s3 = h ? pb1 : pb3; \
    float m = 0.f; \
    { const float q = k0 + __shfl_xor(s0, 32, 64); m += __expf(fmaf(-0.5f, q, (h ? ws[WS_LC + 4] : ws[WS_LC + 0]) + jn)); } \
    { const float q = k1 + __shfl_xor(s1, 32, 64); m += __expf(fmaf(-0.5f, q, (h ? ws[WS_LC + 5] : ws[WS_LC + 1]) + jn)); } \
    { const float q = k2 + __shfl_xor(s2, 32, 64); m += __expf(fmaf(-0.5f, q, (h ? ws[WS_LC + 6] : ws[WS_LC + 2]) + jn)); } \
    { const float q = k3 + __shfl_xor(s3, 32, 64); m += __expf(fmaf(-0.5f, q, (h ? ws[WS_LC + 7] : ws[WS_LC + 3]) + jn)); } \
    m += __shfl_xor(m, 32, 64); \
    if (!h && row < nrows) nll -= __logf(m); }

    TILE(0)
    TILE(1)
#undef TILE
#undef PAIR

#pragma unroll
    for (int off = 32; off > 0; off >>= 1) nll += __shfl_down(nll, off, 64);
    if (lane == 0) red[wid] = nll;
    __syncthreads();
    if (tid == 0) partials[blockIdx.x] = red[0] + red[1] + red[2] + red[3];
}

__global__ __launch_bounds__(256) void gmm_reduce(const float* __restrict__ partials,
                                                  float* __restrict__ out, int nb) {
    __shared__ float red[4];
    const int tid = threadIdx.x;
    float s = 0.f;
    for (int i = tid; i < nb; i += 256) s += partials[i];
#pragma unroll
    for (int off = 32; off > 0; off >>= 1) s += __shfl_down(s, off, 64);
    if ((tid & 63) == 0) red[tid >> 6] = s;
    __syncthreads();
    if (tid == 0) out[0] = red[0] + red[1] + red[2] + red[3];
}

extern "C" void kernel_launch(void* const* d_in, const int* in_sizes, int n_in,
                              void* d_out, int out_size, void* d_ws, size_t ws_size,
                              hipStream_t stream) {
    const float* X       = (const float*)d_in[0];
    const float* lambdas = (const float*)d_in[1];
    const float* mus     = (const float*)d_in[2];
    const float* sigmas  = (const float*)d_in[3];
    const float* w       = (const float*)d_in[4];
    float* out = (float*)d_out;
    float* ws  = (float*)d_ws;

    const int nrows = in_sizes[0] / P;        // 524288
    const int nblocks = (nrows + 255) / 256;  // 2048

    gmm_prep<<<1, 128, 0, stream>>>(lambdas, mus, sigmas, w, ws);
    gmm_main<<<nblocks, 256, 0, stream>>>(X, ws, ws + WS_PART, nrows);
    gmm_reduce<<<1, 256, 0, stream>>>(ws + WS_PART, out, nblocks);
}